// Round 6
// baseline (1504.548 us; speedup 1.0000x reference)
//
#include <hip/hip_runtime.h>

// Residual VQ: B=8,T=4096,D=128 -> N=32768 rows; 8 codebooks x 1024 codes.
// Outputs concat in d_out (float): codes [N*8], quantized [N*128], loss [1].
// R8: R7 structure (MB=64, 8 waves x 8 rows, codes wave-wide, PC=512/NPASS=2,
// 8x8 thread tile, LDS-resident cross-pass argmin, [k4][code] XOR-swizzled B)
// with B staged via __builtin_amdgcn_global_load_lds (width=16): no VGPR
// round-trip, so the 8 in-flight staging float4s (32 VGPRs) that pushed the
// hot-loop live set past 128 and caused R5/R7's scratch thrash are gone.
// LDS dest is linear (HW: uniform base + lane*16); the XOR swizzle is applied
// by pre-swizzling the per-lane GLOBAL source address (slot kk*512+sc loads
// code sc^kk), reproducing R7's conflict-free layout bit-for-bit.

#define N_ROWS 32768
#define DIM    128
#define KCB    1024
#define NCB    8
#define MB     64          // rows per block
#define PC     512         // codes per pass
#define NPASS  (KCB / PC)  // 2
#define KH     32          // k-chunk size (floats)
#define NCHUNK (DIM / KH)  // 4
#define LDA    132         // padded LDS row stride for A (floats)

typedef __attribute__((address_space(1))) const void GLOBv;
typedef __attribute__((address_space(3))) void LDSv;

__global__ __launch_bounds__(256) void zero_ws_kernel(double* lws) {
    if (threadIdx.x < NCB) lws[threadIdx.x] = 0.0;
}

// c2[code] = numpy-pairwise sum over k of cb[code][k]^2 (n=128 pairwise, 8 accums)
__global__ __launch_bounds__(256) void c2_kernel(const float* __restrict__ cbw,
                                                 float* __restrict__ c2g) {
#pragma clang fp contract(off)
    int code = blockIdx.x * 256 + threadIdx.x;  // 0..8191
    const float* row = cbw + (size_t)code * DIM;
    float s[8];
    for (int j = 0; j < 8; ++j) { float x = row[j]; s[j] = x * x; }
    for (int m = 1; m < 16; ++m)
        for (int j = 0; j < 8; ++j) { float x = row[m * 8 + j]; float p = x * x; s[j] += p; }
    c2g[code] = ((s[0] + s[1]) + (s[2] + s[3])) + ((s[4] + s[5]) + (s[6] + s[7]));
}

__global__ __launch_bounds__(512, 1) void rvq_kernel(
    const float* __restrict__ emb, const float* __restrict__ cbw,
    const float* __restrict__ c2g, float* __restrict__ out,
    double* __restrict__ lws)
{
    __shared__ __align__(16) float a_lds[MB * LDA];   // residual [row][k] (33792 B)
    __shared__ float4 b_lds4[8 * PC];                 // B k-chunk [k4][code] (65536 B)
    __shared__ float r2_lds[MB];
    __shared__ float c2_lds[PC];
    __shared__ float scr[8 * MB];                     // pairwise partials
    __shared__ float minv_lds[MB];                    // cross-pass argmin value
    __shared__ int   mini_lds[MB];                    // cross-pass argmin index
    __shared__ int   codes_lds[NCB * MB];

    const int tid  = threadIdx.x;
    const int tcol = tid & 63;   // 64 code-columns: codes tcol+64j, j<8
    const int trow = tid >> 6;   // 8 waves: wave w owns rows w*8 + i, i<8
    const size_t base = (size_t)blockIdx.x * MB;

    // ---- stage embeddings -> a_lds (residual): 2048 float4s, 4 per thread ----
#pragma unroll
    for (int s = 0; s < 4; ++s) {
        int f4 = s * 512 + tid;
        int r = f4 >> 5, k4 = f4 & 31;
        float4 v = *(const float4*)(emb + (base + r) * DIM + (size_t)k4 * 4);
        *(float4*)(a_lds + r * LDA + k4 * 4) = v;
    }
    __syncthreads();

    // ---- initial r2: numpy pairwise (8 accums s_j; thread tid>>6 handles j=q) ----
    {
#pragma clang fp contract(off)
        int r = tid & 63, q = tid >> 6;   // q in 0..7
        float x = a_lds[r * LDA + q];  float s = x * x;
        for (int m = 1; m < 16; ++m) {
            float y = a_lds[r * LDA + m * 8 + q]; float p = y * y; s += p;
        }
        scr[q * MB + r] = s;
    }
    __syncthreads();
    if (tid < MB) {
#pragma clang fp contract(off)
        float t0 = scr[tid],          t1 = scr[MB + tid],
              t2 = scr[2 * MB + tid], t3 = scr[3 * MB + tid],
              t4 = scr[4 * MB + tid], t5 = scr[5 * MB + tid],
              t6 = scr[6 * MB + tid], t7 = scr[7 * MB + tid];
        r2_lds[tid] = ((t0 + t1) + (t2 + t3)) + ((t4 + t5) + (t6 + t7));
    }
    // (pass-0 chunk-0 barrier below covers r2_lds/minv_lds visibility)

#pragma clang loop unroll(disable)
    for (int cb = 0; cb < NCB; ++cb) {
        const float* cbbase = cbw + (size_t)cb * KCB * DIM;
        if (tid < MB) minv_lds[tid] = 3.4e38f;   // barrier inside pass-0 chunk-0 orders this

#pragma clang loop unroll(disable)
        for (int pass = 0; pass < NPASS; ++pass) {
            float acc[8][8];
#pragma unroll
            for (int i = 0; i < 8; ++i)
#pragma unroll
                for (int j = 0; j < 8; ++j) acc[i][j] = 0.f;

#pragma clang loop unroll(disable)
            for (int chunk = 0; chunk < NCHUNK; ++chunk) {
                __syncthreads();  // prior chunk's b_lds reads done; a_lds/r2/minv visible
                // stage B chunk [kk][code] via global_load_lds (HBM/L2 -> LDS,
                // no VGPRs). LDS slot L = s*512 + wv*64 + lane holds code
                // (wv*64+lane)^s at k4=s: pre-swizzled source, linear dest.
                {
                    const float* bsrc = cbbase + (size_t)pass * PC * DIM + chunk * KH;
                    const int wv = trow, lane = tcol;
                    int sc = wv * 64 + lane;          // code-slot 0..511
#pragma unroll
                    for (int s = 0; s < 8; ++s) {
                        const float* g = bsrc + (size_t)(sc ^ s) * DIM + s * 4;
                        float4* l = b_lds4 + s * PC + wv * 64;   // wave-uniform base
                        __builtin_amdgcn_global_load_lds((GLOBv*)g, (LDSv*)l, 16, 0, 0);
                    }
                }
                if (chunk == 0) c2_lds[tid] = c2g[cb * KCB + pass * PC + tid];
                __syncthreads();  // drains vmcnt(0): staged data visible

                // dots: 8 rows x 8 codes per thread, k ascending fp32 fma chains.
                // av: wave-uniform address -> broadcast, bank-free.
                // bv: lane tcol reads slot (tcol^k4)+64j -> permutation of 64
                //     contiguous float4s: conflict-free (stored code = tcol+64j).
                const float* abw = a_lds + trow * 8 * LDA + chunk * KH;
#pragma unroll
                for (int k4 = 0; k4 < 8; ++k4) {
                    const int bx = tcol ^ k4;
                    float4 bv[8];
#pragma unroll
                    for (int j = 0; j < 8; ++j)
                        bv[j] = b_lds4[k4 * PC + bx + 64 * j];
#pragma unroll
                    for (int i = 0; i < 8; ++i) {
                        float4 av = *(const float4*)(abw + i * LDA + k4 * 4);
#pragma unroll
                        for (int j = 0; j < 8; ++j) {
                            acc[i][j] = fmaf(av.x, bv[j].x, acc[i][j]);
                            acc[i][j] = fmaf(av.y, bv[j].y, acc[i][j]);
                            acc[i][j] = fmaf(av.z, bv[j].z, acc[i][j]);
                            acc[i][j] = fmaf(av.w, bv[j].w, acc[i][j]);
                        }
                    }
                }
            }

            // per-pass epilogue: d2 = fl(fl(r2 - 2*dot) + c2); in-thread scan
            // (ascending cg, strict <) -> wave argmin -> lane0 merges into LDS.
            {
#pragma clang fp contract(off)
                float c2v[8];
#pragma unroll
                for (int j = 0; j < 8; ++j) c2v[j] = c2_lds[tcol + 64 * j];
#pragma unroll
                for (int i = 0; i < 8; ++i) {
                    float r2v = r2_lds[trow * 8 + i];
                    float v = 3.4e38f; int ix = 0;
#pragma unroll
                    for (int j = 0; j < 8; ++j) {
                        float t  = r2v - 2.0f * acc[i][j];
                        float d2 = t + c2v[j];
                        int   cg = pass * PC + tcol + 64 * j;
                        if (d2 < v) { v = d2; ix = cg; }
                    }
#pragma unroll
                    for (int m = 1; m <= 32; m <<= 1) {
                        float v2 = __shfl_xor(v, m, 64);
                        int  ix2 = __shfl_xor(ix, m, 64);
                        if (v2 < v || (v2 == v && ix2 < ix)) { v = v2; ix = ix2; }
                    }
                    if (tcol == 0) {
                        int rr = trow * 8 + i;
                        if (v < minv_lds[rr]) { minv_lds[rr] = v; mini_lds[rr] = ix; }
                    }
                }
            }
        }
        __syncthreads();  // mini_lds visible to all threads

        // residual update + loss + next-r2 pairwise partials (numpy order preserved)
        {
#pragma clang fp contract(off)
            int r = tid & 63, q = tid >> 6;
            int widx = mini_lds[r];
            if (q == 0) codes_lds[cb * MB + r] = widx;
            const float* ql = cbbase + (size_t)widx * DIM;
            float s = 0.f;
            double lacc = 0.0;
            for (int m = 0; m < 16; ++m) {
                int k = m * 8 + q;
                float a = a_lds[r * LDA + k];
                float qv = ql[k];
                float n = a - qv;             // new residual (exact ref op)
                a_lds[r * LDA + k] = n;
                float p = n * n;              // loss element, fp32-rounded
                if (m == 0) s = p; else s += p;
                lacc += (double)p;
            }
            scr[q * MB + r] = s;
            for (int off = 32; off > 0; off >>= 1) lacc += __shfl_down(lacc, off, 64);
            if ((tid & 63) == 0) atomicAdd(&lws[cb], lacc);
        }
        __syncthreads();
        if (tid < MB) {
#pragma clang fp contract(off)
            float t0 = scr[tid],          t1 = scr[MB + tid],
                  t2 = scr[2 * MB + tid], t3 = scr[3 * MB + tid],
                  t4 = scr[4 * MB + tid], t5 = scr[5 * MB + tid],
                  t6 = scr[6 * MB + tid], t7 = scr[7 * MB + tid];
            r2_lds[tid] = ((t0 + t1) + (t2 + t3)) + ((t4 + t5) + (t6 + t7));
        }
    }
    __syncthreads();

    // ---- write codes (as float) ----
    if (tid < MB) {
        int r = tid;
        float4 u, v;
        u.x = (float)codes_lds[0 * MB + r]; u.y = (float)codes_lds[1 * MB + r];
        u.z = (float)codes_lds[2 * MB + r]; u.w = (float)codes_lds[3 * MB + r];
        v.x = (float)codes_lds[4 * MB + r]; v.y = (float)codes_lds[5 * MB + r];
        v.z = (float)codes_lds[6 * MB + r]; v.w = (float)codes_lds[7 * MB + r];
        *(float4*)(out + (base + r) * NCB)     = u;
        *(float4*)(out + (base + r) * NCB + 4) = v;
    }

    // ---- quantized = emb + (quant - emb), quant = sequential fp32 sum of codewords ----
    {
#pragma clang fp contract(off)
        int r = tid >> 3, q8 = tid & 7;      // 8 threads per row, 16 k each
        size_t rg = base + r;
        int cds[NCB];
#pragma unroll
        for (int cb = 0; cb < NCB; ++cb) cds[cb] = codes_lds[cb * MB + r];
        float* qout = out + (size_t)N_ROWS * NCB;
#pragma unroll
        for (int ii = 0; ii < 4; ++ii) {
            int k = q8 * 16 + ii * 4;
            float4 qv = make_float4(0.f, 0.f, 0.f, 0.f);
#pragma unroll
            for (int cb = 0; cb < NCB; ++cb) {
                float4 cv = *(const float4*)(cbw + ((size_t)cb * KCB + cds[cb]) * DIM + k);
                qv.x += cv.x; qv.y += cv.y; qv.z += cv.z; qv.w += cv.w;
            }
            float4 ev = *(const float4*)(emb + rg * DIM + k);
            float4 ov;
            ov.x = ev.x + (qv.x - ev.x);
            ov.y = ev.y + (qv.y - ev.y);
            ov.z = ev.z + (qv.z - ev.z);
            ov.w = ev.w + (qv.w - ev.w);
            *(float4*)(qout + rg * DIM + k) = ov;
        }
    }
}

__global__ __launch_bounds__(64) void finish_loss_kernel(const double* __restrict__ lws,
                                                         float* __restrict__ out_loss) {
    if (threadIdx.x == 0 && blockIdx.x == 0) {
        float l = 0.f;
        for (int cb = 0; cb < NCB; ++cb) {
            float m = (float)(lws[cb] / 4194304.0);  // mean over N*D
            l = l + m;                               // fp32 sequential adds (ref order)
        }
        out_loss[0] = l / 8.0f;
    }
}

extern "C" void kernel_launch(void* const* d_in, const int* in_sizes, int n_in,
                              void* d_out, int out_size, void* d_ws, size_t ws_size,
                              hipStream_t stream) {
    const float* emb = (const float*)d_in[0];   // [32768,128] fp32
    const float* cbw = (const float*)d_in[1];   // [8,1024,128] fp32
    float* out = (float*)d_out;
    double* lws = (double*)d_ws;                         // 8 doubles
    float* c2g = (float*)((char*)d_ws + 256);            // 8192 floats

    hipLaunchKernelGGL(zero_ws_kernel, dim3(1), dim3(64), 0, stream, lws);
    hipLaunchKernelGGL(c2_kernel, dim3(32), dim3(256), 0, stream, cbw, c2g);
    hipLaunchKernelGGL(rvq_kernel, dim3(512), dim3(512), 0, stream, emb, cbw, c2g, out, lws);
    hipLaunchKernelGGL(finish_loss_kernel, dim3(1), dim3(64), 0, stream, lws,
                       out + (size_t)N_ROWS * NCB + (size_t)N_ROWS * DIM);
}

// Round 7
// 1165.859 us; speedup vs baseline: 1.2905x; 1.2905x over previous
//
#include <hip/hip_runtime.h>

// Residual VQ: B=8,T=4096,D=128 -> N=32768 rows; 8 codebooks x 1024 codes.
// Outputs concat in d_out (float): codes [N*8], quantized [N*128], loss [1].
// R9: R2 shell (MB=128, 256 blocks = 1/CU, simple padded strides, reg staging,
// proven residual/r2/loss phases) with the 16-instr/256-FMA dot tiling:
// wave owns 16 rows as two 8-row half-wave groups; 32 code-cols x Nj=8
// (PC=256, NPASS=4, K chunked 2x64). av: 2-addr broadcast (free);
// bv: stride 68 floats = 17 quads == 1 mod 8 -> conflict-free b128.
// Cross-pass argmin lives in LDS; hot-loop core = acc64 + bv32 + av stream.

#define N_ROWS 32768
#define DIM    128
#define KCB    1024
#define NCB    8
#define MB     128         // rows per block
#define PC     256         // codes per pass
#define NPASS  (KCB / PC)  // 4
#define KH     64          // k-chunk size (floats)
#define NCHUNK (DIM / KH)  // 2
#define LDA    132         // padded LDS row stride for A (floats): 33 quads, 1 mod 8
#define LDB    68          // padded LDS row stride for B (floats): 17 quads, 1 mod 8

__global__ __launch_bounds__(256) void zero_ws_kernel(double* lws) {
    if (threadIdx.x < NCB) lws[threadIdx.x] = 0.0;
}

// c2[code] = numpy-pairwise sum over k of cb[code][k]^2 (n=128 pairwise, 8 accums)
__global__ __launch_bounds__(256) void c2_kernel(const float* __restrict__ cbw,
                                                 float* __restrict__ c2g) {
#pragma clang fp contract(off)
    int code = blockIdx.x * 256 + threadIdx.x;  // 0..8191
    const float* row = cbw + (size_t)code * DIM;
    float s[8];
    for (int j = 0; j < 8; ++j) { float x = row[j]; s[j] = x * x; }
    for (int m = 1; m < 16; ++m)
        for (int j = 0; j < 8; ++j) { float x = row[m * 8 + j]; float p = x * x; s[j] += p; }
    c2g[code] = ((s[0] + s[1]) + (s[2] + s[3])) + ((s[4] + s[5]) + (s[6] + s[7]));
}

__global__ __launch_bounds__(512, 1) void rvq_kernel(
    const float* __restrict__ emb, const float* __restrict__ cbw,
    const float* __restrict__ c2g, float* __restrict__ out,
    double* __restrict__ lws)
{
    __shared__ __align__(16) float a_lds[MB * LDA];   // residual [row][k]   (67584 B)
    __shared__ __align__(16) float b_lds[PC * LDB];   // B k-chunk [code][kk] (69632 B)
    __shared__ float r2_lds[MB];
    __shared__ float c2_lds[PC];
    __shared__ float scr[4 * MB];                     // pairwise partials
    __shared__ float minv_lds[MB];                    // cross-pass argmin value
    __shared__ int   mini_lds[MB];                    // cross-pass argmin index
    __shared__ int   codes_lds[NCB * MB];

    const int tid  = threadIdx.x;
    const int tcol = tid & 31;        // 32 code-columns: codes tcol+32j, j<8
    const int half = (tid >> 5) & 1;  // half-wave row group
    const int trow = tid >> 6;        // wave id: rows trow*16 + half*8 + i, i<8
    const size_t base = (size_t)blockIdx.x * MB;

    // ---- stage embeddings -> a_lds (residual): 4096 float4s, 8 per thread ----
#pragma unroll
    for (int s = 0; s < 8; ++s) {
        int f4 = s * 512 + tid;          // 0..4095
        int r = f4 >> 5, k4 = f4 & 31;
        float4 v = *(const float4*)(emb + (base + r) * DIM + (size_t)k4 * 4);
        *(float4*)(a_lds + r * LDA + k4 * 4) = v;
    }
    __syncthreads();

    // ---- initial r2: numpy pairwise (8 accums s_j; thread handles j in {2q,2q+1}) ----
    {
#pragma clang fp contract(off)
        int r = tid & 127, q = tid >> 7;   // q in 0..3
        float x0 = a_lds[r * LDA + 2 * q];     float s0 = x0 * x0;
        float x1 = a_lds[r * LDA + 2 * q + 1]; float s1 = x1 * x1;
        for (int m = 1; m < 16; ++m) {
            float y0 = a_lds[r * LDA + m * 8 + 2 * q];     float p0 = y0 * y0; s0 += p0;
            float y1 = a_lds[r * LDA + m * 8 + 2 * q + 1]; float p1 = y1 * y1; s1 += p1;
        }
        scr[q * MB + r] = s0 + s1;
    }
    __syncthreads();
    if (tid < MB) {
#pragma clang fp contract(off)
        float t0 = scr[tid], t1 = scr[MB + tid], t2 = scr[2 * MB + tid], t3 = scr[3 * MB + tid];
        r2_lds[tid] = (t0 + t1) + (t2 + t3);
    }
    // (pass-0 chunk-0 barrier below covers r2_lds/minv_lds visibility)

#pragma clang loop unroll(disable)
    for (int cb = 0; cb < NCB; ++cb) {
        const float* cbbase = cbw + (size_t)cb * KCB * DIM;
        if (tid < MB) minv_lds[tid] = 3.4e38f;

#pragma clang loop unroll(disable)
        for (int pass = 0; pass < NPASS; ++pass) {
            float acc[8][8];
#pragma unroll
            for (int i = 0; i < 8; ++i)
#pragma unroll
                for (int j = 0; j < 8; ++j) acc[i][j] = 0.f;

#pragma clang loop unroll(disable)
            for (int chunk = 0; chunk < NCHUNK; ++chunk) {
                __syncthreads();  // prior chunk's b_lds reads done; a_lds/r2/minv visible
                // stage B chunk [code][kk]: 256 codes x 16 f4, 8 f4 per thread.
                // write quad = (17c + kk) mod 8 = (c+kk) mod 8 -> 8 lanes/quad: free.
                const float* bsrc = cbbase + (size_t)pass * PC * DIM + chunk * KH;
#pragma unroll
                for (int s = 0; s < 8; ++s) {
                    int f4 = s * 512 + tid;      // 0..4095
                    int c = f4 >> 4, kk = f4 & 15;
                    float4 v = *(const float4*)(bsrc + (size_t)c * DIM + kk * 4);
                    *(float4*)(b_lds + c * LDB + kk * 4) = v;
                }
                if (chunk == 0 && tid < PC) c2_lds[tid] = c2g[cb * KCB + pass * PC + tid];
                __syncthreads();

                // dots: 8 rows x 8 codes per thread, k ascending fp32 fma chains.
                // bv[8] held (32 regs), av streamed per row (broadcast read).
                const float* abw = a_lds + (trow * 16 + half * 8) * LDA + chunk * KH;
                const float* bvb = b_lds + tcol * LDB;
#pragma unroll
                for (int k4 = 0; k4 < 16; ++k4) {
                    float4 bv[8];
#pragma unroll
                    for (int j = 0; j < 8; ++j)
                        bv[j] = *(const float4*)(bvb + j * 32 * LDB + k4 * 4);
#pragma unroll
                    for (int i = 0; i < 8; ++i) {
                        float4 av = *(const float4*)(abw + i * LDA + k4 * 4);
#pragma unroll
                        for (int j = 0; j < 8; ++j) {
                            acc[i][j] = fmaf(av.x, bv[j].x, acc[i][j]);
                            acc[i][j] = fmaf(av.y, bv[j].y, acc[i][j]);
                            acc[i][j] = fmaf(av.z, bv[j].z, acc[i][j]);
                            acc[i][j] = fmaf(av.w, bv[j].w, acc[i][j]);
                        }
                    }
                }
            }

            // per-pass epilogue: d2 = fl(fl(r2 - 2*dot) + c2); in-thread scan
            // (ascending cg, strict <) -> 32-lane half-wave argmin -> lane
            // tcol==0 of each half merges its rows into LDS (strict <).
            {
#pragma clang fp contract(off)
                float c2v[8];
#pragma unroll
                for (int j = 0; j < 8; ++j) c2v[j] = c2_lds[tcol + 32 * j];
#pragma unroll
                for (int i = 0; i < 8; ++i) {
                    int rr = trow * 16 + half * 8 + i;
                    float r2v = r2_lds[rr];
                    float v = 3.4e38f; int ix = 0;
#pragma unroll
                    for (int j = 0; j < 8; ++j) {
                        float t  = r2v - 2.0f * acc[i][j];
                        float d2 = t + c2v[j];
                        int   cg = pass * PC + tcol + 32 * j;
                        if (d2 < v) { v = d2; ix = cg; }
                    }
#pragma unroll
                    for (int m = 1; m <= 16; m <<= 1) {   // stays within 32-lane half
                        float v2 = __shfl_xor(v, m, 64);
                        int  ix2 = __shfl_xor(ix, m, 64);
                        if (v2 < v || (v2 == v && ix2 < ix)) { v = v2; ix = ix2; }
                    }
                    if (tcol == 0) {
                        if (v < minv_lds[rr]) { minv_lds[rr] = v; mini_lds[rr] = ix; }
                    }
                }
            }
        }
        __syncthreads();  // mini_lds visible to all threads

        // residual update + loss + next-r2 pairwise partials (numpy order preserved)
        {
#pragma clang fp contract(off)
            int r = tid & 127, q = tid >> 7;
            int widx = mini_lds[r];
            if (q == 0) codes_lds[cb * MB + r] = widx;
            const float* ql = cbbase + (size_t)widx * DIM;
            float s0 = 0.f, s1 = 0.f;
            double lacc = 0.0;
            for (int m = 0; m < 16; ++m) {
                int k0 = m * 8 + 2 * q;
                float a0 = a_lds[r * LDA + k0];
                float q0 = ql[k0];
                float n0 = a0 - q0;           // new residual (exact ref op)
                a_lds[r * LDA + k0] = n0;
                float p0 = n0 * n0;           // loss element, fp32-rounded
                if (m == 0) s0 = p0; else s0 += p0;
                lacc += (double)p0;
                int k1 = k0 + 1;
                float a1 = a_lds[r * LDA + k1];
                float q1 = ql[k1];
                float n1 = a1 - q1;
                a_lds[r * LDA + k1] = n1;
                float p1 = n1 * n1;
                if (m == 0) s1 = p1; else s1 += p1;
                lacc += (double)p1;
            }
            scr[q * MB + r] = s0 + s1;
            for (int off = 32; off > 0; off >>= 1) lacc += __shfl_down(lacc, off, 64);
            if ((tid & 63) == 0) atomicAdd(&lws[cb], lacc);
        }
        __syncthreads();
        if (tid < MB) {
#pragma clang fp contract(off)
            float t0 = scr[tid], t1 = scr[MB + tid], t2 = scr[2 * MB + tid], t3 = scr[3 * MB + tid];
            r2_lds[tid] = (t0 + t1) + (t2 + t3);
        }
    }
    __syncthreads();

    // ---- write codes (as float) ----
    if (tid < MB) {
        int r = tid;
        float4 u, v;
        u.x = (float)codes_lds[0 * MB + r]; u.y = (float)codes_lds[1 * MB + r];
        u.z = (float)codes_lds[2 * MB + r]; u.w = (float)codes_lds[3 * MB + r];
        v.x = (float)codes_lds[4 * MB + r]; v.y = (float)codes_lds[5 * MB + r];
        v.z = (float)codes_lds[6 * MB + r]; v.w = (float)codes_lds[7 * MB + r];
        *(float4*)(out + (base + r) * NCB)     = u;
        *(float4*)(out + (base + r) * NCB + 4) = v;
    }

    // ---- quantized = emb + (quant - emb), quant = sequential fp32 sum of codewords ----
    {
#pragma clang fp contract(off)
        int r = tid >> 2, q4 = tid & 3;
        size_t rg = base + r;
        int cds[NCB];
#pragma unroll
        for (int cb = 0; cb < NCB; ++cb) cds[cb] = codes_lds[cb * MB + r];
        float* qout = out + (size_t)N_ROWS * NCB;
#pragma unroll
        for (int ii = 0; ii < 8; ++ii) {
            int k = q4 * 32 + ii * 4;
            float4 qv = make_float4(0.f, 0.f, 0.f, 0.f);
#pragma unroll
            for (int cb = 0; cb < NCB; ++cb) {
                float4 cv = *(const float4*)(cbw + ((size_t)cb * KCB + cds[cb]) * DIM + k);
                qv.x += cv.x; qv.y += cv.y; qv.z += cv.z; qv.w += cv.w;
            }
            float4 ev = *(const float4*)(emb + rg * DIM + k);
            float4 ov;
            ov.x = ev.x + (qv.x - ev.x);
            ov.y = ev.y + (qv.y - ev.y);
            ov.z = ev.z + (qv.z - ev.z);
            ov.w = ev.w + (qv.w - ev.w);
            *(float4*)(qout + rg * DIM + k) = ov;
        }
    }
}

__global__ __launch_bounds__(64) void finish_loss_kernel(const double* __restrict__ lws,
                                                         float* __restrict__ out_loss) {
    if (threadIdx.x == 0 && blockIdx.x == 0) {
        float l = 0.f;
        for (int cb = 0; cb < NCB; ++cb) {
            float m = (float)(lws[cb] / 4194304.0);  // mean over N*D
            l = l + m;                               // fp32 sequential adds (ref order)
        }
        out_loss[0] = l / 8.0f;
    }
}

extern "C" void kernel_launch(void* const* d_in, const int* in_sizes, int n_in,
                              void* d_out, int out_size, void* d_ws, size_t ws_size,
                              hipStream_t stream) {
    const float* emb = (const float*)d_in[0];   // [32768,128] fp32
    const float* cbw = (const float*)d_in[1];   // [8,1024,128] fp32
    float* out = (float*)d_out;
    double* lws = (double*)d_ws;                         // 8 doubles
    float* c2g = (float*)((char*)d_ws + 256);            // 8192 floats

    hipLaunchKernelGGL(zero_ws_kernel, dim3(1), dim3(64), 0, stream, lws);
    hipLaunchKernelGGL(c2_kernel, dim3(32), dim3(256), 0, stream, cbw, c2g);
    hipLaunchKernelGGL(rvq_kernel, dim3(256), dim3(512), 0, stream, emb, cbw, c2g, out, lws);
    hipLaunchKernelGGL(finish_loss_kernel, dim3(1), dim3(64), 0, stream, lws,
                       out + (size_t)N_ROWS * NCB + (size_t)N_ROWS * DIM);
}